// Round 5
// baseline (507.567 us; speedup 1.0000x reference)
//
#include <hip/hip_runtime.h>
#include <math.h>

#define MIN_NORM 1e-15f

// B=32, S=256, V=30000, L=1024, H=4, D=64

// ---- fast scalar helpers ----
__device__ __forceinline__ float frcp(float x){ return __builtin_amdgcn_rcpf(x); }
__device__ __forceinline__ float fsqrt(float x){ return __builtin_amdgcn_sqrtf(x); }
__device__ __forceinline__ float fast_atanh(float x){        // x in [0, 1-1e-7]
  return 0.5f * __logf((1.f + x) * frcp(1.f - x));
}
__device__ __forceinline__ float fast_tanh(float y){         // y >= 0
  float e = __expf(-2.f * y);
  return (1.f - e) * frcp(1.f + e);
}

// ---- DPP wave64 sum reductions (result broadcast via readlane 63) ----
#define DPPADD(v, ctrl) \
  v += __int_as_float(__builtin_amdgcn_update_dpp(0, __float_as_int(v), ctrl, 0xf, 0xf, false));

__device__ __forceinline__ float wred_b(float v){
  DPPADD(v,0x111) DPPADD(v,0x112) DPPADD(v,0x114) DPPADD(v,0x118)
  DPPADD(v,0x142) DPPADD(v,0x143)
  return __int_as_float(__builtin_amdgcn_readlane(__float_as_int(v), 63));
}
__device__ __forceinline__ void wred3_b(float& v0, float& v1, float& v2){
  DPPADD(v0,0x111) DPPADD(v1,0x111) DPPADD(v2,0x111)
  DPPADD(v0,0x112) DPPADD(v1,0x112) DPPADD(v2,0x112)
  DPPADD(v0,0x114) DPPADD(v1,0x114) DPPADD(v2,0x114)
  DPPADD(v0,0x118) DPPADD(v1,0x118) DPPADD(v2,0x118)
  DPPADD(v0,0x142) DPPADD(v1,0x142) DPPADD(v2,0x142)
  DPPADD(v0,0x143) DPPADD(v1,0x143) DPPADD(v2,0x143)
  v0 = __int_as_float(__builtin_amdgcn_readlane(__float_as_int(v0), 63));
  v1 = __int_as_float(__builtin_amdgcn_readlane(__float_as_int(v1), 63));
  v2 = __int_as_float(__builtin_amdgcn_readlane(__float_as_int(v2), 63));
}

__device__ __forceinline__ float wred(float v){   // shfl version (TLP-rich kernels)
#pragma unroll
  for(int o=32;o;o>>=1) v += __shfl_xor(v, o, 64);
  return v;
}

#define LDS_FENCE() asm volatile("s_waitcnt lgkmcnt(0)" ::: "memory")

// 64-dot-product: RES = sum_j WROW[j]*HSARR[j]; 8 accumulators for ILP.
#define MATVEC64(RES, WROW, HSARR) {                                     \
  float a0=0.f,a1=0.f,a2=0.f,a3=0.f,a4=0.f,a5=0.f,a6=0.f,a7=0.f;         \
  _Pragma("unroll")                                                      \
  for(int j=0;j<64;j+=8){                                                \
    float4 h4 = *(const float4*)(&(HSARR)[j]);                           \
    float4 h5 = *(const float4*)(&(HSARR)[j+4]);                         \
    a0 = fmaf((WROW)[j  ], h4.x, a0); a1 = fmaf((WROW)[j+1], h4.y, a1);  \
    a2 = fmaf((WROW)[j+2], h4.z, a2); a3 = fmaf((WROW)[j+3], h4.w, a3);  \
    a4 = fmaf((WROW)[j+4], h5.x, a4); a5 = fmaf((WROW)[j+5], h5.y, a5);  \
    a6 = fmaf((WROW)[j+6], h5.z, a6); a7 = fmaf((WROW)[j+7], h5.w, a7);  \
  }                                                                      \
  RES = ((a0+a1)+(a2+a3)) + ((a4+a5)+(a6+a7));                           \
}

// ---- kernel 1: ux = mobius_matvec(U, wemb[x]); wux = W.ux; uxn2=||ux||^2; uxb=ux.b ----
__global__ __launch_bounds__(256) void k_ux(const int* __restrict__ x,
    const float* __restrict__ wemb, const float* __restrict__ U,
    const float* __restrict__ Wm, const float* __restrict__ bvec,
    float* __restrict__ ux, float* __restrict__ wux,
    float* __restrict__ uxn2, float* __restrict__ uxb){
  __shared__ __align__(16) float xs[4][64];
  const int wv = threadIdx.x >> 6, lane = threadIdx.x & 63;
  const int bid = blockIdx.x*4 + wv;   // (b*S+s)*4 + h
  const int h = bid & 3;
  const int bs = bid >> 2;
  const int v = x[bs];
  float xi = wemb[(size_t)v*256 + h*64 + lane];
  const float bi = bvec[h*64 + lane];
  xs[wv][lane] = xi;
  LDS_FENCE();
  float mx; MATVEC64(mx, U + h*4096 + lane*64, xs[wv]);
  float t0 = xi*xi, t1 = mx*mx, t2 = mx*bi;
  wred3_b(t0, t1, t2);         // t0=||x||^2, t1=||mx||^2, t2=mx.b
  float xn  = fmaxf(fsqrt(t0), MIN_NORM);
  float mxn = fmaxf(fsqrt(t1), MIN_NORM);
  float scale = fast_tanh(mxn*frcp(xn) * fast_atanh(fminf(xn, 1.f-1e-7f)));
  float sm = scale * frcp(mxn);
  float uxv = sm * mx;                    // mx==0 -> 0
  ux[(size_t)bid*64 + lane] = uxv;
  if(lane==0){
    uxn2[bid] = (t1 > 0.f) ? scale*scale : 0.f;
    uxb[bid]  = sm * t2;
  }
  // second matvec: wux = W . ux  (feeds k_rnn's m-space recurrence)
  xs[wv][lane] = uxv;                     // same-wave DS ops are in-order: safe reuse
  LDS_FENCE();
  float wuv; MATVEC64(wuv, Wm + h*4096 + lane*64, xs[wv]);
  wux[(size_t)bid*64 + lane] = wuv;
}

// ---- kernel 2: sequential Mobius RNN in m-space (m = W.h) ----
// h_{s+1} = al*m + be*u + ga*b  (al,be,ga wave-uniform scalars)
// m_{s+1} = al*(W.m) + be*Wu_s + ga*Wb   -> broadcast+matvec chain (LDS) and
// reduce+tail chain (DPP) are independent; they join in 3 FMAs.
// ||h||^2 carried analytically; enc_s computed per-lane from the basis.
#define RNN_STEP(S, USLOT, WUSLOT, Y2SLOT, UBSLOT) {                     \
  hs[lane] = m;                             /* broadcast m_s */          \
  const float U_ = USLOT, WU_ = WUSLOT, Y2_ = Y2SLOT, UB_ = UBSLOT;      \
  if((S) < 254){                            /* depth-2 prefetch */       \
    USLOT  = uxp  [(size_t)((S)+2)*256 + lane];                          \
    WUSLOT = wuxp [(size_t)((S)+2)*256 + lane];                          \
    Y2SLOT = uxn2p[((S)+2)*4];                                           \
    UBSLOT = uxbp [((S)+2)*4];                                           \
  }                                                                      \
  float p0 = m*m, p1 = m*U_, p2 = m*bi;                                  \
  wred3_b(p0, p1, p2);                      /* DPP overlaps ds_write */  \
  LDS_FENCE();                                                           \
  float r_; MATVEC64(r_, wrow, hs);         /* r = W.m, overlaps tail */ \
  float xn  = fmaxf(fsqrt(hh), MIN_NORM);                                \
  float mxn = fmaxf(fsqrt(p0), MIN_NORM);                                \
  float at  = fast_atanh(fminf(xn, 1.f-1e-7f));                          \
  float scale = fast_tanh(mxn*frcp(xn)*at);                              \
  float sm  = scale*frcp(mxn);                                           \
  float wx2 = (p0 > 0.f) ? scale*scale : 0.f;                            \
  float xy  = sm*p1;                                                     \
  float A   = 1.f + 2.f*xy + Y2_;                                        \
  float Bc  = 1.f - wx2;                                                 \
  float iden = frcp(fmaxf(1.f + 2.f*xy + wx2*Y2_, MIN_NORM));            \
  float c1 = A*sm*iden, c2 = Bc*iden;                                    \
  float zz = (A*A*wx2 + 2.f*A*Bc*xy + Bc*Bc*Y2_)*iden*iden;              \
  float zb = (A*sm*p2 + Bc*UB_)*iden;                                    \
  float A2 = 1.f + 2.f*zb + bn2v;                                        \
  float B2 = 1.f - zz;                                                   \
  float iden2 = frcp(fmaxf(1.f + 2.f*zb + zz*bn2v, MIN_NORM));           \
  float e  = A2*iden2, ga = B2*iden2;                                    \
  float al = e*c1, be = e*c2;                                            \
  encp[(size_t)(S)*256 + lane] = fmaf(al, m, fmaf(be, U_, ga*bi));       \
  hh = fmaxf(e*e*zz + 2.f*e*ga*zb + ga*ga*bn2v, 0.f);                    \
  m  = fmaf(al, r_, fmaf(be, WU_, ga*wb));                               \
}

__global__ __launch_bounds__(64) void k_rnn(const float* __restrict__ W,
    const float* __restrict__ bvec, const float* __restrict__ ux,
    const float* __restrict__ wux, const float* __restrict__ uxn2,
    const float* __restrict__ uxb, float* __restrict__ enc){
  const int b = blockIdx.x >> 2, h = blockIdx.x & 3;
  const int lane = threadIdx.x;
  float wrow[64];
  const float* Wp = W + h*4096 + lane*64;
#pragma unroll
  for(int j=0;j<64;j+=4){
    float4 w4 = *(const float4*)(Wp + j);
    wrow[j]=w4.x; wrow[j+1]=w4.y; wrow[j+2]=w4.z; wrow[j+3]=w4.w;
  }
  const float bi = bvec[h*64 + lane];
  __shared__ __align__(16) float hs[64];
  // preamble: bn2 = ||b||^2 and wb = W.b (one-time broadcast matvec)
  hs[lane] = bi;
  const float bn2v = wred_b(bi*bi);
  LDS_FENCE();
  float wb; MATVEC64(wb, wrow, hs);
  const float* uxp   = ux   + (size_t)b*65536 + h*64;   // + s*256 + lane
  const float* wuxp  = wux  + (size_t)b*65536 + h*64;
  const float* uxn2p = uxn2 + (size_t)b*1024  + h;      // + s*4
  const float* uxbp  = uxb  + (size_t)b*1024  + h;
  float* encp        = enc  + (size_t)b*65536 + h*64;
  // prefetch s=0 (slot A) and s=1 (slot B)
  float uA  = uxp[lane],         wuA = wuxp[lane];
  float y2A = uxn2p[0],          ubA = uxbp[0];
  float uB  = uxp[256+lane],     wuB = wuxp[256+lane];
  float y2B = uxn2p[4],          ubB = uxbp[4];
  float m = 0.f, hh = 0.f;       // h_0 = 0  ->  m_0 = W.h_0 = 0
  for(int s=0;s<256;s+=2){
    RNN_STEP(s,   uA, wuA, y2A, ubA);
    RNN_STEP(s+1, uB, wuB, y2B, ubB);
  }
}

// ---- row squared-norms: src is [nrows][64] ----
__global__ __launch_bounds__(256) void k_norm2(const float* __restrict__ src,
    float* __restrict__ dst, int nrows){
  const int row = blockIdx.x*4 + (threadIdx.x>>6);
  const int lane = threadIdx.x & 63;
  if(row >= nrows) return;
  float v = src[(size_t)row*64 + lane];
  float n2 = wred(v*v);
  if(lane==0) dst[row] = n2;
}

// acosh(1+y) = log(1 + y + sqrt(y*(2+y))) — cancellation-free, ~13 VALU ops
// vs libm acoshf's ~350-400 (measured: acoshf was 85% of k_dist's VALU issue).
__device__ __forceinline__ float pdist(float dot, float a, float lb){
  float c2  = fmaxf(a + lb - 2.f*dot, 0.f);
  float iden = frcp(fmaxf((1.f-a)*(1.f-lb), MIN_NORM));
  float y   = fmaxf(2.f*c2*iden, 1e-7f);     // == max(arg,1+1e-7) semantics
  return __logf(1.f + y + fsqrt(y*(2.f+y)));
}

// ---- kernel 3: interaction[b,l,s] = sum_h poinc_dist(enc[b,s,h],lab[l,h]) ----
#define LP 68  // padded LDS stride (64 + 4), keeps b128 16B-aligned, kills conflicts
__global__ __launch_bounds__(256) void k_dist(const float* __restrict__ enc,
    const float* __restrict__ lab, const float* __restrict__ an,
    const float* __restrict__ lbn, float* __restrict__ inter){
  __shared__ __align__(16) float eT[4*16*LP];
  __shared__ __align__(16) float lT[4*16*LP];
  const int bs0 = blockIdx.x*64, l0 = blockIdx.y*64;
  const int t = threadIdx.x;
  const int tr = t>>4, tc = t&15;
  const int ldr = t>>2, ldp = t&3;
  float acc[4][4][4];
#pragma unroll
  for(int h=0;h<4;h++)
#pragma unroll
    for(int i=0;i<4;i++)
#pragma unroll
      for(int j=0;j<4;j++) acc[h][i][j]=0.f;

  for(int c=0;c<4;c++){
    if(c) __syncthreads();
#pragma unroll
    for(int h=0;h<4;h++){
      float4 ev = *(const float4*)&enc[(size_t)(bs0+ldr)*256 + h*64 + c*16 + ldp*4];
      float4 lv = *(const float4*)&lab[(size_t)(l0 +ldr)*256 + h*64 + c*16 + ldp*4];
      int base = (h*16 + ldp*4)*LP + ldr;
      eT[base     ] = ev.x; eT[base+  LP] = ev.y; eT[base+2*LP] = ev.z; eT[base+3*LP] = ev.w;
      lT[base     ] = lv.x; lT[base+  LP] = lv.y; lT[base+2*LP] = lv.z; lT[base+3*LP] = lv.w;
    }
    __syncthreads();
#pragma unroll
    for(int dd=0;dd<16;dd++){
#pragma unroll
      for(int h=0;h<4;h++){
        float4 e4 = *(const float4*)&eT[(h*16+dd)*LP + tr*4];
        float4 l4 = *(const float4*)&lT[(h*16+dd)*LP + tc*4];
        float ee[4] = {e4.x,e4.y,e4.z,e4.w};
        float ll[4] = {l4.x,l4.y,l4.z,l4.w};
#pragma unroll
        for(int i=0;i<4;i++)
#pragma unroll
          for(int j=0;j<4;j++)
            acc[h][i][j] = fmaf(ee[i], ll[j], acc[h][i][j]);
      }
    }
  }
  const int b = bs0 >> 8;
#pragma unroll
  for(int i=0;i<4;i++){
    const int bs = bs0 + tr*4 + i;
    const int s  = bs & 255;
    float4 ah = *(const float4*)&an[(size_t)bs*4];
#pragma unroll
    for(int j=0;j<4;j++){
      const int l = l0 + tc*4 + j;
      float4 lb = *(const float4*)&lbn[(size_t)l*4];
      float d = pdist(acc[0][i][j], ah.x, lb.x)
              + pdist(acc[1][i][j], ah.y, lb.y)
              + pdist(acc[2][i][j], ah.z, lb.z)
              + pdist(acc[3][i][j], ah.w, lb.w);
      inter[((size_t)b*1024 + l)*256 + s] = d;
    }
  }
}

// ---- kernel 4: out[b,l] = w2 . relu(w1 @ inter[b,l,:] + b1) + b2 ----
__global__ __launch_bounds__(256) void k_mlp(const float* __restrict__ inter,
    const float* __restrict__ w1, const float* __restrict__ b1,
    const float* __restrict__ w2, const float* __restrict__ b2,
    float* __restrict__ out){
  __shared__ __align__(16) float rows[32*256];
  __shared__ float part[4][16];
  const int b  = blockIdx.x >> 5;
  const int l0 = (blockIdx.x & 31)*32;
  const int t = threadIdx.x;
  const float* ip = inter + ((size_t)b*1024 + l0)*256;
#pragma unroll
  for(int k=0;k<8;k++){
    int idx = k*1024 + t*4;
    *(float4*)&rows[idx] = *(const float4*)&ip[idx];
  }
  __syncthreads();
  const int f = t & 127, g = t >> 7;
  float acc[16];
#pragma unroll
  for(int li=0;li<16;li++) acc[li]=0.f;
  const float* wp = w1 + (size_t)f*256;
  for(int s=0;s<256;s+=4){
    float4 w4 = *(const float4*)&wp[s];
#pragma unroll
    for(int li=0;li<16;li++){
      float4 r4 = *(const float4*)&rows[(g*16+li)*256 + s];
      acc[li] = fmaf(r4.w, w4.w, fmaf(r4.z, w4.z, fmaf(r4.y, w4.y, fmaf(r4.x, w4.x, acc[li]))));
    }
  }
  const float bb1 = b1[f], ww2 = w2[f];
  const int wave = t>>6, lane = t&63;
#pragma unroll
  for(int li=0;li<16;li++){
    float vv = fmaxf(acc[li] + bb1, 0.f) * ww2;
    vv = wred(vv);
    if(lane==0) part[wave][li] = vv;
  }
  __syncthreads();
  if(t < 32){
    int g2 = t>>4, li = t&15;
    out[(size_t)b*1024 + l0 + g2*16 + li] = part[2*g2][li] + part[2*g2+1][li] + b2[0];
  }
}

extern "C" void kernel_launch(void* const* d_in, const int* in_sizes, int n_in,
                              void* d_out, int out_size, void* d_ws, size_t ws_size,
                              hipStream_t stream){
  const int*   x    = (const int*)d_in[0];
  const float* wemb = (const float*)d_in[1];
  const float* lab  = (const float*)d_in[2];
  const float* W    = (const float*)d_in[3];
  const float* U    = (const float*)d_in[4];
  const float* bv   = (const float*)d_in[5];
  const float* w1   = (const float*)d_in[6];
  const float* b1   = (const float*)d_in[7];
  const float* w2   = (const float*)d_in[8];
  const float* b2   = (const float*)d_in[9];
  float* out = (float*)d_out;

  float* ws    = (float*)d_ws;
  float* enc   = ws;                      // 2,097,152 f  [B*S*H][64]
  float* an    = enc + 2097152;           //    32,768 f  [B*S*H]
  float* lbn   = an  + 32768;             //     4,096 f  [L*H]
  float* ux    = lbn + 4096;              // 2,097,152 f  (dead after k_rnn)
  float* uxn2  = ux  + 2097152;           //    32,768 f
  float* uxb   = uxn2 + 32768;            //    32,768 f
  float* wux   = uxb + 32768;             // 2,097,152 f  (dead after k_rnn)
  float* inter = lbn + 4096;              // 8,388,608 f  [B][L][S] (overlaps ux..wux)
  // peak ws use: 2134016 + 8388608 floats ≈ 42.1 MB (unchanged)

  k_ux   <<<8192, 256, 0, stream>>>(x, wemb, U, W, bv, ux, wux, uxn2, uxb);
  k_norm2<<<1024, 256, 0, stream>>>(lab, lbn, 4096);
  k_rnn  <<<128,   64, 0, stream>>>(W, bv, ux, wux, uxn2, uxb, enc);
  k_norm2<<<8192, 256, 0, stream>>>(enc, an, 32768);
  dim3 g3(128, 16);
  k_dist <<<g3,   256, 0, stream>>>(enc, lab, an, lbn, inter);
  k_mlp  <<<1024, 256, 0, stream>>>(inter, w1, b1, w2, b2, out);
}

// Round 6
// 492.628 us; speedup vs baseline: 1.0303x; 1.0303x over previous
//
#include <hip/hip_runtime.h>
#include <math.h>

#define MIN_NORM 1e-15f

// B=32, S=256, V=30000, L=1024, H=4, D=64

// ---- fast scalar helpers ----
__device__ __forceinline__ float frcp(float x){ return __builtin_amdgcn_rcpf(x); }
__device__ __forceinline__ float fsqrt(float x){ return __builtin_amdgcn_sqrtf(x); }
__device__ __forceinline__ float fast_atanh(float x){        // x in [0, 1-1e-7]
  return 0.5f * __logf((1.f + x) * frcp(1.f - x));
}
__device__ __forceinline__ float fast_tanh(float y){         // y >= 0
  float e = __expf(-2.f * y);
  return (1.f - e) * frcp(1.f + e);
}
__device__ __forceinline__ float rdlane(float v, int l){     // runtime lane idx OK
  return __int_as_float(__builtin_amdgcn_readlane(__float_as_int(v), l));
}

// ---- DPP wave64 sum reductions (result broadcast via readlane 63) ----
#define DPPADD(v, ctrl) \
  v += __int_as_float(__builtin_amdgcn_update_dpp(0, __float_as_int(v), ctrl, 0xf, 0xf, false));

__device__ __forceinline__ float wred_b(float v){
  DPPADD(v,0x111) DPPADD(v,0x112) DPPADD(v,0x114) DPPADD(v,0x118)
  DPPADD(v,0x142) DPPADD(v,0x143)
  return __int_as_float(__builtin_amdgcn_readlane(__float_as_int(v), 63));
}
__device__ __forceinline__ void wred3_b(float& v0, float& v1, float& v2){
  DPPADD(v0,0x111) DPPADD(v1,0x111) DPPADD(v2,0x111)
  DPPADD(v0,0x112) DPPADD(v1,0x112) DPPADD(v2,0x112)
  DPPADD(v0,0x114) DPPADD(v1,0x114) DPPADD(v2,0x114)
  DPPADD(v0,0x118) DPPADD(v1,0x118) DPPADD(v2,0x118)
  DPPADD(v0,0x142) DPPADD(v1,0x142) DPPADD(v2,0x142)
  DPPADD(v0,0x143) DPPADD(v1,0x143) DPPADD(v2,0x143)
  v0 = __int_as_float(__builtin_amdgcn_readlane(__float_as_int(v0), 63));
  v1 = __int_as_float(__builtin_amdgcn_readlane(__float_as_int(v1), 63));
  v2 = __int_as_float(__builtin_amdgcn_readlane(__float_as_int(v2), 63));
}

__device__ __forceinline__ float wred(float v){   // shfl version (TLP-rich kernels)
#pragma unroll
  for(int o=32;o;o>>=1) v += __shfl_xor(v, o, 64);
  return v;
}

#define LDS_FENCE() asm volatile("s_waitcnt lgkmcnt(0)" ::: "memory")

// 64-dot-product: RES = sum_j WROW[j]*HSARR[j]; 8 accumulators for ILP.
#define MATVEC64(RES, WROW, HSARR) {                                     \
  float a0=0.f,a1=0.f,a2=0.f,a3=0.f,a4=0.f,a5=0.f,a6=0.f,a7=0.f;         \
  _Pragma("unroll")                                                      \
  for(int j=0;j<64;j+=8){                                                \
    float4 h4 = *(const float4*)(&(HSARR)[j]);                           \
    float4 h5 = *(const float4*)(&(HSARR)[j+4]);                         \
    a0 = fmaf((WROW)[j  ], h4.x, a0); a1 = fmaf((WROW)[j+1], h4.y, a1);  \
    a2 = fmaf((WROW)[j+2], h4.z, a2); a3 = fmaf((WROW)[j+3], h4.w, a3);  \
    a4 = fmaf((WROW)[j+4], h5.x, a4); a5 = fmaf((WROW)[j+5], h5.y, a5);  \
    a6 = fmaf((WROW)[j+6], h5.z, a6); a7 = fmaf((WROW)[j+7], h5.w, a7);  \
  }                                                                      \
  RES = ((a0+a1)+(a2+a3)) + ((a4+a5)+(a6+a7));                           \
}

// ---- kernel 1: ux = mobius_matvec(U, wemb[x]); wux = W.ux; uxn2=||ux||^2; uxb=ux.b ----
__global__ __launch_bounds__(256) void k_ux(const int* __restrict__ x,
    const float* __restrict__ wemb, const float* __restrict__ U,
    const float* __restrict__ Wm, const float* __restrict__ bvec,
    float* __restrict__ ux, float* __restrict__ wux,
    float* __restrict__ uxn2, float* __restrict__ uxb){
  __shared__ __align__(16) float xs[4][64];
  const int wv = threadIdx.x >> 6, lane = threadIdx.x & 63;
  const int bid = blockIdx.x*4 + wv;   // (b*S+s)*4 + h
  const int h = bid & 3;
  const int bs = bid >> 2;
  const int v = x[bs];
  float xi = wemb[(size_t)v*256 + h*64 + lane];
  const float bi = bvec[h*64 + lane];
  xs[wv][lane] = xi;
  LDS_FENCE();
  float mx; MATVEC64(mx, U + h*4096 + lane*64, xs[wv]);
  float t0 = xi*xi, t1 = mx*mx, t2 = mx*bi;
  wred3_b(t0, t1, t2);         // t0=||x||^2, t1=||mx||^2, t2=mx.b
  float xn  = fmaxf(fsqrt(t0), MIN_NORM);
  float mxn = fmaxf(fsqrt(t1), MIN_NORM);
  float scale = fast_tanh(mxn*frcp(xn) * fast_atanh(fminf(xn, 1.f-1e-7f)));
  float sm = scale * frcp(mxn);
  float uxv = sm * mx;                    // mx==0 -> 0
  ux[(size_t)bid*64 + lane] = uxv;
  if(lane==0){
    uxn2[bid] = (t1 > 0.f) ? scale*scale : 0.f;
    uxb[bid]  = sm * t2;
  }
  // second matvec: wux = W . ux  (feeds k_rnn's m-space recurrence)
  xs[wv][lane] = uxv;                     // same-wave DS ops are in-order: safe reuse
  LDS_FENCE();
  float wuv; MATVEC64(wuv, Wm + h*4096 + lane*64, xs[wv]);
  wux[(size_t)bid*64 + lane] = wuv;
}

// ---- kernel 2: sequential Mobius RNN in m-space (m = W.h) ----
// h_{s+1} = al*m + be*u + ga*b ; m_{s+1} = al*(W.m) + be*Wu_s + ga*Wb.
// Per-step scalars (||u||^2, u.b) preloaded into 8 VGPRs (lane ℓ of reg blk
// holds step blk*64+ℓ) and fetched via v_readlane — the loop contains NO
// SMEM/uniform loads, so the lgkmcnt fence only orders the hs ds_write.
// (Round-5 lesson: uniform s_load + lgkmcnt(0) fence = full L2 drain/step.)
#define RNN_STEP(S, USLOT, WUSLOT, Y2V, UBV) {                           \
  hs[lane] = m;                             /* broadcast m_s */          \
  const float U_ = USLOT, WU_ = WUSLOT;                                  \
  const float Y2_ = (Y2V), UB_ = (UBV);                                  \
  if((S) < 254){                            /* depth-2 prefetch */       \
    USLOT  = uxp  [(size_t)((S)+2)*256 + lane];                          \
    WUSLOT = wuxp [(size_t)((S)+2)*256 + lane];                          \
  }                                                                      \
  float p0 = m*m, p1 = m*U_, p2 = m*bi;                                  \
  wred3_b(p0, p1, p2);                      /* DPP overlaps ds_write */  \
  LDS_FENCE();                                                           \
  float r_; MATVEC64(r_, wrow, hs);         /* r = W.m, overlaps tail */ \
  float xn  = fmaxf(fsqrt(hh), MIN_NORM);                                \
  float mxn = fmaxf(fsqrt(p0), MIN_NORM);                                \
  float at  = fast_atanh(fminf(xn, 1.f-1e-7f));                          \
  float scale = fast_tanh(mxn*frcp(xn)*at);                              \
  float sm  = scale*frcp(mxn);                                           \
  float wx2 = (p0 > 0.f) ? scale*scale : 0.f;                            \
  float xy  = sm*p1;                                                     \
  float A   = 1.f + 2.f*xy + Y2_;                                        \
  float Bc  = 1.f - wx2;                                                 \
  float iden = frcp(fmaxf(1.f + 2.f*xy + wx2*Y2_, MIN_NORM));            \
  float c1 = A*sm*iden, c2 = Bc*iden;                                    \
  float zz = (A*A*wx2 + 2.f*A*Bc*xy + Bc*Bc*Y2_)*iden*iden;              \
  float zb = (A*sm*p2 + Bc*UB_)*iden;                                    \
  float A2 = 1.f + 2.f*zb + bn2v;                                        \
  float B2 = 1.f - zz;                                                   \
  float iden2 = frcp(fmaxf(1.f + 2.f*zb + zz*bn2v, MIN_NORM));           \
  float e  = A2*iden2, ga = B2*iden2;                                    \
  float al = e*c1, be = e*c2;                                            \
  encp[(size_t)(S)*256 + lane] = fmaf(al, m, fmaf(be, U_, ga*bi));       \
  hh = fmaxf(e*e*zz + 2.f*e*ga*zb + ga*ga*bn2v, 0.f);                    \
  m  = fmaf(al, r_, fmaf(be, WU_, ga*wb));                               \
}

#define RNN_BLOCK(BLK, Y2R, UBR)                                         \
  for(int i=0;i<64;i+=2){                                                \
    RNN_STEP((BLK)*64+i,   uA, wuA, rdlane(Y2R, i),   rdlane(UBR, i));   \
    RNN_STEP((BLK)*64+i+1, uB, wuB, rdlane(Y2R, i+1), rdlane(UBR, i+1)); \
  }

__global__ __launch_bounds__(64) void k_rnn(const float* __restrict__ W,
    const float* __restrict__ bvec, const float* __restrict__ ux,
    const float* __restrict__ wux, const float* __restrict__ uxn2,
    const float* __restrict__ uxb, float* __restrict__ enc){
  const int b = blockIdx.x >> 2, h = blockIdx.x & 3;
  const int lane = threadIdx.x;
  float wrow[64];
  const float* Wp = W + h*4096 + lane*64;
#pragma unroll
  for(int j=0;j<64;j+=4){
    float4 w4 = *(const float4*)(Wp + j);
    wrow[j]=w4.x; wrow[j+1]=w4.y; wrow[j+2]=w4.z; wrow[j+3]=w4.w;
  }
  const float bi = bvec[h*64 + lane];
  __shared__ __align__(16) float hs[64];
  // preamble: bn2 = ||b||^2 and wb = W.b (one-time broadcast matvec)
  hs[lane] = bi;
  const float bn2v = wred_b(bi*bi);
  LDS_FENCE();
  float wb; MATVEC64(wb, wrow, hs);
  const float* uxp   = ux   + (size_t)b*65536 + h*64;   // + s*256 + lane
  const float* wuxp  = wux  + (size_t)b*65536 + h*64;
  const float* uxn2p = uxn2 + (size_t)b*1024  + h;      // + s*4
  const float* uxbp  = uxb  + (size_t)b*1024  + h;
  float* encp        = enc  + (size_t)b*65536 + h*64;
  // scalar tables -> 8 VGPRs: lane ℓ of reg blk holds step blk*64+ℓ
  float y2r0 = uxn2p[(      lane)*4], ubr0 = uxbp[(      lane)*4];
  float y2r1 = uxn2p[( 64 + lane)*4], ubr1 = uxbp[( 64 + lane)*4];
  float y2r2 = uxn2p[(128 + lane)*4], ubr2 = uxbp[(128 + lane)*4];
  float y2r3 = uxn2p[(192 + lane)*4], ubr3 = uxbp[(192 + lane)*4];
  // prefetch s=0 (slot A) and s=1 (slot B)
  float uA  = uxp[lane],         wuA = wuxp[lane];
  float uB  = uxp[256+lane],     wuB = wuxp[256+lane];
  float m = 0.f, hh = 0.f;       // h_0 = 0  ->  m_0 = W.h_0 = 0
  RNN_BLOCK(0, y2r0, ubr0)
  RNN_BLOCK(1, y2r1, ubr1)
  RNN_BLOCK(2, y2r2, ubr2)
  RNN_BLOCK(3, y2r3, ubr3)
}

// ---- row squared-norms: src is [nrows][64] ----
__global__ __launch_bounds__(256) void k_norm2(const float* __restrict__ src,
    float* __restrict__ dst, int nrows){
  const int row = blockIdx.x*4 + (threadIdx.x>>6);
  const int lane = threadIdx.x & 63;
  if(row >= nrows) return;
  float v = src[(size_t)row*64 + lane];
  float n2 = wred(v*v);
  if(lane==0) dst[row] = n2;
}

// acosh(1+y) = log(1 + y + sqrt(y*(2+y))) — cancellation-free, ~13 VALU ops
// vs libm acoshf's ~350-400 (measured: acoshf was 85% of k_dist's VALU issue).
__device__ __forceinline__ float pdist(float dot, float a, float lb){
  float c2  = fmaxf(a + lb - 2.f*dot, 0.f);
  float iden = frcp(fmaxf((1.f-a)*(1.f-lb), MIN_NORM));
  float y   = fmaxf(2.f*c2*iden, 1e-7f);     // == max(arg,1+1e-7) semantics
  return __logf(1.f + y + fsqrt(y*(2.f+y)));
}

// ---- kernel 3: interaction[b,l,s] = sum_h poinc_dist(enc[b,s,h],lab[l,h]) ----
#define LP 68  // padded LDS stride (64 + 4), keeps b128 16B-aligned, kills conflicts
__global__ __launch_bounds__(256) void k_dist(const float* __restrict__ enc,
    const float* __restrict__ lab, const float* __restrict__ an,
    const float* __restrict__ lbn, float* __restrict__ inter){
  __shared__ __align__(16) float eT[4*16*LP];
  __shared__ __align__(16) float lT[4*16*LP];
  const int bs0 = blockIdx.x*64, l0 = blockIdx.y*64;
  const int t = threadIdx.x;
  const int tr = t>>4, tc = t&15;
  const int ldr = t>>2, ldp = t&3;
  float acc[4][4][4];
#pragma unroll
  for(int h=0;h<4;h++)
#pragma unroll
    for(int i=0;i<4;i++)
#pragma unroll
      for(int j=0;j<4;j++) acc[h][i][j]=0.f;

  for(int c=0;c<4;c++){
    if(c) __syncthreads();
#pragma unroll
    for(int h=0;h<4;h++){
      float4 ev = *(const float4*)&enc[(size_t)(bs0+ldr)*256 + h*64 + c*16 + ldp*4];
      float4 lv = *(const float4*)&lab[(size_t)(l0 +ldr)*256 + h*64 + c*16 + ldp*4];
      int base = (h*16 + ldp*4)*LP + ldr;
      eT[base     ] = ev.x; eT[base+  LP] = ev.y; eT[base+2*LP] = ev.z; eT[base+3*LP] = ev.w;
      lT[base     ] = lv.x; lT[base+  LP] = lv.y; lT[base+2*LP] = lv.z; lT[base+3*LP] = lv.w;
    }
    __syncthreads();
#pragma unroll
    for(int dd=0;dd<16;dd++){
#pragma unroll
      for(int h=0;h<4;h++){
        float4 e4 = *(const float4*)&eT[(h*16+dd)*LP + tr*4];
        float4 l4 = *(const float4*)&lT[(h*16+dd)*LP + tc*4];
        float ee[4] = {e4.x,e4.y,e4.z,e4.w};
        float ll[4] = {l4.x,l4.y,l4.z,l4.w};
#pragma unroll
        for(int i=0;i<4;i++)
#pragma unroll
          for(int j=0;j<4;j++)
            acc[h][i][j] = fmaf(ee[i], ll[j], acc[h][i][j]);
      }
    }
  }
  const int b = bs0 >> 8;
#pragma unroll
  for(int i=0;i<4;i++){
    const int bs = bs0 + tr*4 + i;
    const int s  = bs & 255;
    float4 ah = *(const float4*)&an[(size_t)bs*4];
#pragma unroll
    for(int j=0;j<4;j++){
      const int l = l0 + tc*4 + j;
      float4 lb = *(const float4*)&lbn[(size_t)l*4];
      float d = pdist(acc[0][i][j], ah.x, lb.x)
              + pdist(acc[1][i][j], ah.y, lb.y)
              + pdist(acc[2][i][j], ah.z, lb.z)
              + pdist(acc[3][i][j], ah.w, lb.w);
      inter[((size_t)b*1024 + l)*256 + s] = d;
    }
  }
}

// ---- kernel 4: out[b,l] = w2 . relu(w1 @ inter[b,l,:] + b1) + b2 ----
__global__ __launch_bounds__(256) void k_mlp(const float* __restrict__ inter,
    const float* __restrict__ w1, const float* __restrict__ b1,
    const float* __restrict__ w2, const float* __restrict__ b2,
    float* __restrict__ out){
  __shared__ __align__(16) float rows[32*256];
  __shared__ float part[4][16];
  const int b  = blockIdx.x >> 5;
  const int l0 = (blockIdx.x & 31)*32;
  const int t = threadIdx.x;
  const float* ip = inter + ((size_t)b*1024 + l0)*256;
#pragma unroll
  for(int k=0;k<8;k++){
    int idx = k*1024 + t*4;
    *(float4*)&rows[idx] = *(const float4*)&ip[idx];
  }
  __syncthreads();
  const int f = t & 127, g = t >> 7;
  float acc[16];
#pragma unroll
  for(int li=0;li<16;li++) acc[li]=0.f;
  const float* wp = w1 + (size_t)f*256;
  for(int s=0;s<256;s+=4){
    float4 w4 = *(const float4*)&wp[s];
#pragma unroll
    for(int li=0;li<16;li++){
      float4 r4 = *(const float4*)&rows[(g*16+li)*256 + s];
      acc[li] = fmaf(r4.w, w4.w, fmaf(r4.z, w4.z, fmaf(r4.y, w4.y, fmaf(r4.x, w4.x, acc[li]))));
    }
  }
  const float bb1 = b1[f], ww2 = w2[f];
  const int wave = t>>6, lane = t&63;
#pragma unroll
  for(int li=0;li<16;li++){
    float vv = fmaxf(acc[li] + bb1, 0.f) * ww2;
    vv = wred(vv);
    if(lane==0) part[wave][li] = vv;
  }
  __syncthreads();
  if(t < 32){
    int g2 = t>>4, li = t&15;
    out[(size_t)b*1024 + l0 + g2*16 + li] = part[2*g2][li] + part[2*g2+1][li] + b2[0];
  }
}

extern "C" void kernel_launch(void* const* d_in, const int* in_sizes, int n_in,
                              void* d_out, int out_size, void* d_ws, size_t ws_size,
                              hipStream_t stream){
  const int*   x    = (const int*)d_in[0];
  const float* wemb = (const float*)d_in[1];
  const float* lab  = (const float*)d_in[2];
  const float* W    = (const float*)d_in[3];
  const float* U    = (const float*)d_in[4];
  const float* bv   = (const float*)d_in[5];
  const float* w1   = (const float*)d_in[6];
  const float* b1   = (const float*)d_in[7];
  const float* w2   = (const float*)d_in[8];
  const float* b2   = (const float*)d_in[9];
  float* out = (float*)d_out;

  float* ws    = (float*)d_ws;
  float* enc   = ws;                      // 2,097,152 f  [B*S*H][64]
  float* an    = enc + 2097152;           //    32,768 f  [B*S*H]
  float* lbn   = an  + 32768;             //     4,096 f  [L*H]
  float* ux    = lbn + 4096;              // 2,097,152 f  (dead after k_rnn)
  float* uxn2  = ux  + 2097152;           //    32,768 f
  float* uxb   = uxn2 + 32768;            //    32,768 f
  float* wux   = uxb + 32768;             // 2,097,152 f  (dead after k_rnn)
  float* inter = lbn + 4096;              // 8,388,608 f  [B][L][S] (overlaps ux..wux)
  // peak ws use: 2134016 + 8388608 floats ≈ 42.1 MB (unchanged)

  k_ux   <<<8192, 256, 0, stream>>>(x, wemb, U, W, bv, ux, wux, uxn2, uxb);
  k_norm2<<<1024, 256, 0, stream>>>(lab, lbn, 4096);
  k_rnn  <<<128,   64, 0, stream>>>(W, bv, ux, wux, uxn2, uxb, enc);
  k_norm2<<<8192, 256, 0, stream>>>(enc, an, 32768);
  dim3 g3(128, 16);
  k_dist <<<g3,   256, 0, stream>>>(enc, lab, an, lbn, inter);
  k_mlp  <<<1024, 256, 0, stream>>>(inter, w1, b1, w2, b2, out);
}